// Round 1
// baseline (235.763 us; speedup 1.0000x reference)
//
#include <hip/hip_runtime.h>
#include <hip/hip_bf16.h>

#define F 128
#define ROWS 32        // rows per block in support kernel
#define SCAN_T 256
#define SCAN_B 256

// ---------------------------------------------------------------------------
// support = (x * sigmoid(x@node_w) * softmax(sem_w)) @ weight
// One block = 32 rows. W (64KB) staged in LDS, x tile (16KB) in LDS,
// 4x4 register tile per thread (256 threads: 8 row-groups x 32 col-groups).
// ---------------------------------------------------------------------------
__global__ __launch_bounds__(256) void support_kernel(
    const float* __restrict__ x, const float* __restrict__ weight,
    const float* __restrict__ node_w, const float* __restrict__ sem_w,
    float* __restrict__ support, int n_rows)
{
    __shared__ __align__(16) float W_lds[F * F];     // [k][c] 64KB
    __shared__ __align__(16) float xs[ROWS * F];     // [r][k] 16KB (scaled x)
    __shared__ __align__(16) float sem[F];
    __shared__ float natt[ROWS];

    const int t = threadIdx.x;
    const int rbase = blockIdx.x * ROWS;

    // --- semantic softmax (wave 0 only, 128 elems) ---
    if (t < 64) {
        float v0 = sem_w[t], v1 = sem_w[t + 64];
        float m = fmaxf(v0, v1);
        #pragma unroll
        for (int off = 32; off; off >>= 1) m = fmaxf(m, __shfl_xor(m, off));
        float e0 = __expf(v0 - m), e1 = __expf(v1 - m);
        float ssum = e0 + e1;
        #pragma unroll
        for (int off = 32; off; off >>= 1) ssum += __shfl_xor(ssum, off);
        float inv = 1.0f / ssum;
        sem[t] = e0 * inv;
        sem[t + 64] = e1 * inv;
    }

    // --- load W into LDS (coalesced float4) ---
    const float4* W4g = (const float4*)weight;
    float4* W4l = (float4*)W_lds;
    #pragma unroll
    for (int i = 0; i < 16; ++i) W4l[i * 256 + t] = W4g[i * 256 + t];

    // --- stage x tile + node-attention dot partials ---
    // j = t + i*256 indexes 1024 float4s: row r = j>>5, float4-col k4 = j&31.
    const int k4 = t & 31;
    float4 nw4 = ((const float4*)node_w)[k4];
    #pragma unroll
    for (int i = 0; i < 4; ++i) {
        int j = t + i * 256;
        int r = j >> 5;
        int gr = rbase + r;
        float4 v = make_float4(0.f, 0.f, 0.f, 0.f);
        if (gr < n_rows) v = ((const float4*)x)[(size_t)gr * 32 + k4];
        ((float4*)xs)[j] = v;
        float p = v.x * nw4.x + v.y * nw4.y + v.z * nw4.z + v.w * nw4.w;
        // reduce over the 32 lanes of this half-wave (one full row each)
        p += __shfl_xor(p, 1);  p += __shfl_xor(p, 2);  p += __shfl_xor(p, 4);
        p += __shfl_xor(p, 8);  p += __shfl_xor(p, 16);
        if ((t & 31) == 0) natt[r] = p;
    }
    __syncthreads();

    if (t < ROWS) {
        float z = natt[t];
        natt[t] = 1.0f / (1.0f + __expf(-z));
    }
    __syncthreads();

    // --- scale xs in place: xs[r][k] *= natt[r] * sem[k] ---
    #pragma unroll
    for (int i = 0; i < 4; ++i) {
        int j = t + i * 256;
        int r = j >> 5, kk = j & 31;
        float4 v = ((float4*)xs)[j];
        float4 s4 = ((float4*)sem)[kk];
        float a = natt[r];
        v.x *= a * s4.x; v.y *= a * s4.y; v.z *= a * s4.z; v.w *= a * s4.w;
        ((float4*)xs)[j] = v;
    }
    __syncthreads();

    // --- 4x4 register-tiled GEMM: rows 4*rg..+3, cols 4*cg..+3 ---
    const int cg = t & 31;
    const int rg = t >> 5;
    float acc[4][4] = {};
    #pragma unroll 4
    for (int k = 0; k < F; ++k) {
        float4 w = ((float4*)W_lds)[k * 32 + cg];
        #pragma unroll
        for (int i = 0; i < 4; ++i) {
            float s = xs[(4 * rg + i) * F + k];   // broadcast read
            acc[i][0] = fmaf(s, w.x, acc[i][0]);
            acc[i][1] = fmaf(s, w.y, acc[i][1]);
            acc[i][2] = fmaf(s, w.z, acc[i][2]);
            acc[i][3] = fmaf(s, w.w, acc[i][3]);
        }
    }

    #pragma unroll
    for (int i = 0; i < 4; ++i) {
        int r = rbase + 4 * rg + i;
        if (r < n_rows) {
            float4 o = make_float4(acc[i][0], acc[i][1], acc[i][2], acc[i][3]);
            ((float4*)support)[(size_t)r * 32 + cg] = o;
        }
    }
}

// ---------------------------------------------------------------------------
// CSR build: zero -> histogram -> 3-phase scan -> slot scatter
// ---------------------------------------------------------------------------
__global__ void zero_kernel(int* __restrict__ p, int n) {
    int i = blockIdx.x * blockDim.x + threadIdx.x;
    if (i < n) p[i] = 0;
}

__global__ void hist_kernel(const int* __restrict__ dst, int* __restrict__ counts, int e) {
    int i = blockIdx.x * blockDim.x + threadIdx.x;
    if (i < e) atomicAdd(&counts[dst[i]], 1);
}

__global__ void scan_phase1(const int* __restrict__ counts, int* __restrict__ partial,
                            int n, int chunk) {
    __shared__ int s[SCAN_T];
    int b = blockIdx.x, t = threadIdx.x;
    int base = b * chunk;
    int sum = 0;
    for (int i = t; i < chunk; i += SCAN_T) {
        int idx = base + i;
        if (idx < n) sum += counts[idx];
    }
    s[t] = sum; __syncthreads();
    #pragma unroll
    for (int off = 128; off; off >>= 1) {
        if (t < off) s[t] += s[t + off];
        __syncthreads();
    }
    if (t == 0) partial[b] = s[0];
}

__global__ void scan_phase2(int* __restrict__ partial) {
    __shared__ int s[SCAN_T];
    int t = threadIdx.x;
    int v = partial[t];
    s[t] = v; __syncthreads();
    for (int off = 1; off < SCAN_T; off <<= 1) {
        int x = (t >= off) ? s[t - off] : 0;
        __syncthreads();
        s[t] += x;
        __syncthreads();
    }
    partial[t] = s[t] - v;   // exclusive prefix of block sums
}

__global__ void scan_phase3(const int* __restrict__ counts, const int* __restrict__ partial,
                            int* __restrict__ row_ptr, int n, int chunk, int total) {
    __shared__ int s[SCAN_T];
    int b = blockIdx.x, t = threadIdx.x;
    int idx = b * chunk + t;
    int v = (t < chunk && idx < n) ? counts[idx] : 0;
    s[t] = v; __syncthreads();
    for (int off = 1; off < SCAN_T; off <<= 1) {
        int x = (t >= off) ? s[t - off] : 0;
        __syncthreads();
        s[t] += x;
        __syncthreads();
    }
    if (t < chunk && idx < n) row_ptr[idx] = partial[b] + s[t] - v;
    if (b == 0 && t == 0) row_ptr[n] = total;
}

__global__ void scatter_kernel(const int* __restrict__ dst, const int* __restrict__ row_ptr,
                               int* __restrict__ counts, int* __restrict__ edge_idx, int e) {
    int i = blockIdx.x * blockDim.x + threadIdx.x;
    if (i < e) {
        int d = dst[i];
        int old = atomicSub(&counts[d], 1);   // drains counts back to 0
        edge_idx[row_ptr[d] + old - 1] = i;
    }
}

// ---------------------------------------------------------------------------
// Aggregate: one 128-thread block per dst node; register accumulation,
// coalesced 512B gather per edge, no output atomics.
// ---------------------------------------------------------------------------
__global__ __launch_bounds__(128) void aggregate_kernel(
    const float* __restrict__ support, const int* __restrict__ row_ptr,
    const int* __restrict__ edge_idx, const int* __restrict__ src,
    const float* __restrict__ adj_val, const float* __restrict__ bias,
    float* __restrict__ out)
{
    const int n = blockIdx.x, t = threadIdx.x;
    const int i0 = row_ptr[n], i1 = row_ptr[n + 1];
    float acc = 0.f;
    for (int i = i0; i < i1; ++i) {
        int e = edge_idx[i];
        float a = adj_val[e];
        int s = src[e];
        acc = fmaf(a, support[(size_t)s * F + t], acc);
    }
    out[(size_t)n * F + t] = acc + bias[t];
}

// ---------------------------------------------------------------------------
// Fallback (ws too small for CSR): init out with bias, edge-parallel atomics.
// ---------------------------------------------------------------------------
__global__ void init_out_kernel(float* __restrict__ out, const float* __restrict__ bias, int n) {
    int i = blockIdx.x * blockDim.x + threadIdx.x;
    if (i < n) out[i] = bias[i & (F - 1)];
}

__global__ void edge_atomic_kernel(const float* __restrict__ support,
                                   const int* __restrict__ src, const int* __restrict__ dst,
                                   const float* __restrict__ adj_val, float* __restrict__ out, int e) {
    long long g = (long long)blockIdx.x * blockDim.x + threadIdx.x;
    if (g >= (long long)e * 32) return;
    int ed = (int)(g >> 5), q = (int)(g & 31);
    float a = adj_val[ed];
    float4 v = ((const float4*)support)[(size_t)src[ed] * 32 + q];
    float* o = out + (size_t)dst[ed] * F + 4 * q;
    atomicAdd(o + 0, a * v.x);
    atomicAdd(o + 1, a * v.y);
    atomicAdd(o + 2, a * v.z);
    atomicAdd(o + 3, a * v.w);
}

// ---------------------------------------------------------------------------
extern "C" void kernel_launch(void* const* d_in, const int* in_sizes, int n_in,
                              void* d_out, int out_size, void* d_ws, size_t ws_size,
                              hipStream_t stream) {
    const float* x       = (const float*)d_in[0];
    const float* weight  = (const float*)d_in[1];
    const float* node_w  = (const float*)d_in[2];
    const float* sem_w   = (const float*)d_in[3];
    const float* bias    = (const float*)d_in[4];
    const float* adj_val = (const float*)d_in[5];
    const int*   src     = (const int*)d_in[6];
    const int*   dst     = (const int*)d_in[7];
    float* out = (float*)d_out;

    const int Nn = in_sizes[0] / F;     // 40000
    const int Ee = in_sizes[5];         // 640000

    char* ws = (char*)d_ws;
    size_t off = 0;
    auto alloc = [&](size_t bytes) {
        void* p = ws + off;
        off = (off + bytes + 255) & ~(size_t)255;
        return p;
    };
    float* support  = (float*)alloc((size_t)Nn * F * sizeof(float));
    size_t need_atomic = off;
    int* counts   = (int*)alloc((size_t)Nn * sizeof(int));
    int* row_ptr  = (int*)alloc((size_t)(Nn + 1) * sizeof(int));
    int* edge_idx = (int*)alloc((size_t)Ee * sizeof(int));
    int* partial  = (int*)alloc(SCAN_T * sizeof(int));
    size_t need_full = off;

    // Stage 1: support GEMM (sem softmax + node att fused)
    support_kernel<<<(Nn + ROWS - 1) / ROWS, 256, 0, stream>>>(
        x, weight, node_w, sem_w, support, Nn);

    if (ws_size >= need_full) {
        const int chunk = (Nn + SCAN_B - 1) / SCAN_B;   // 157, <= SCAN_T
        zero_kernel<<<(Nn + 255) / 256, 256, 0, stream>>>(counts, Nn);
        hist_kernel<<<(Ee + 255) / 256, 256, 0, stream>>>(dst, counts, Ee);
        scan_phase1<<<SCAN_B, SCAN_T, 0, stream>>>(counts, partial, Nn, chunk);
        scan_phase2<<<1, SCAN_T, 0, stream>>>(partial);
        scan_phase3<<<SCAN_B, SCAN_T, 0, stream>>>(counts, partial, row_ptr, Nn, chunk, Ee);
        scatter_kernel<<<(Ee + 255) / 256, 256, 0, stream>>>(dst, row_ptr, counts, edge_idx, Ee);
        aggregate_kernel<<<Nn, 128, 0, stream>>>(
            support, row_ptr, edge_idx, src, adj_val, bias, out);
    } else if (ws_size >= need_atomic) {
        init_out_kernel<<<((size_t)Nn * F + 255) / 256, 256, 0, stream>>>(out, bias, Nn * F);
        long long tot = (long long)Ee * 32;
        edge_atomic_kernel<<<(unsigned)((tot + 255) / 256), 256, 0, stream>>>(
            support, src, dst, adj_val, out, Ee);
    }
}

// Round 2
// 162.737 us; speedup vs baseline: 1.4487x; 1.4487x over previous
//
#include <hip/hip_runtime.h>
#include <hip/hip_bf16.h>

#define F 128
#define ROWS 32        // rows per block in support kernel
#define SCAN_T 256
#define SCAN_B 256

// ---------------------------------------------------------------------------
// support = (x * sigmoid(x@node_w) * softmax(sem_w)) @ weight
// One block = 32 rows. W (64KB) staged in LDS, x tile (16KB) in LDS,
// 4x4 register tile per thread (256 threads: 8 row-groups x 32 col-groups).
// ---------------------------------------------------------------------------
__global__ __launch_bounds__(256) void support_kernel(
    const float* __restrict__ x, const float* __restrict__ weight,
    const float* __restrict__ node_w, const float* __restrict__ sem_w,
    float* __restrict__ support, int n_rows)
{
    __shared__ __align__(16) float W_lds[F * F];     // [k][c] 64KB
    __shared__ __align__(16) float xs[ROWS * F];     // [r][k] 16KB (scaled x)
    __shared__ __align__(16) float sem[F];
    __shared__ float natt[ROWS];

    const int t = threadIdx.x;
    const int rbase = blockIdx.x * ROWS;

    // --- semantic softmax (wave 0 only, 128 elems) ---
    if (t < 64) {
        float v0 = sem_w[t], v1 = sem_w[t + 64];
        float m = fmaxf(v0, v1);
        #pragma unroll
        for (int off = 32; off; off >>= 1) m = fmaxf(m, __shfl_xor(m, off));
        float e0 = __expf(v0 - m), e1 = __expf(v1 - m);
        float ssum = e0 + e1;
        #pragma unroll
        for (int off = 32; off; off >>= 1) ssum += __shfl_xor(ssum, off);
        float inv = 1.0f / ssum;
        sem[t] = e0 * inv;
        sem[t + 64] = e1 * inv;
    }

    // --- load W into LDS (coalesced float4) ---
    const float4* W4g = (const float4*)weight;
    float4* W4l = (float4*)W_lds;
    #pragma unroll
    for (int i = 0; i < 16; ++i) W4l[i * 256 + t] = W4g[i * 256 + t];

    // --- stage x tile + node-attention dot partials ---
    const int k4 = t & 31;
    float4 nw4 = ((const float4*)node_w)[k4];
    #pragma unroll
    for (int i = 0; i < 4; ++i) {
        int j = t + i * 256;
        int r = j >> 5;
        int gr = rbase + r;
        float4 v = make_float4(0.f, 0.f, 0.f, 0.f);
        if (gr < n_rows) v = ((const float4*)x)[(size_t)gr * 32 + k4];
        ((float4*)xs)[j] = v;
        float p = v.x * nw4.x + v.y * nw4.y + v.z * nw4.z + v.w * nw4.w;
        p += __shfl_xor(p, 1);  p += __shfl_xor(p, 2);  p += __shfl_xor(p, 4);
        p += __shfl_xor(p, 8);  p += __shfl_xor(p, 16);
        if ((t & 31) == 0) natt[r] = p;
    }
    __syncthreads();

    if (t < ROWS) {
        float z = natt[t];
        natt[t] = 1.0f / (1.0f + __expf(-z));
    }
    __syncthreads();

    // --- scale xs in place: xs[r][k] *= natt[r] * sem[k] ---
    #pragma unroll
    for (int i = 0; i < 4; ++i) {
        int j = t + i * 256;
        int r = j >> 5, kk = j & 31;
        float4 v = ((float4*)xs)[j];
        float4 s4 = ((float4*)sem)[kk];
        float a = natt[r];
        v.x *= a * s4.x; v.y *= a * s4.y; v.z *= a * s4.z; v.w *= a * s4.w;
        ((float4*)xs)[j] = v;
    }
    __syncthreads();

    // --- 4x4 register-tiled GEMM ---
    const int cg = t & 31;
    const int rg = t >> 5;
    float acc[4][4] = {};
    #pragma unroll 4
    for (int k = 0; k < F; ++k) {
        float4 w = ((float4*)W_lds)[k * 32 + cg];
        #pragma unroll
        for (int i = 0; i < 4; ++i) {
            float s = xs[(4 * rg + i) * F + k];
            acc[i][0] = fmaf(s, w.x, acc[i][0]);
            acc[i][1] = fmaf(s, w.y, acc[i][1]);
            acc[i][2] = fmaf(s, w.z, acc[i][2]);
            acc[i][3] = fmaf(s, w.w, acc[i][3]);
        }
    }

    #pragma unroll
    for (int i = 0; i < 4; ++i) {
        int r = rbase + 4 * rg + i;
        if (r < n_rows) {
            float4 o = make_float4(acc[i][0], acc[i][1], acc[i][2], acc[i][3]);
            ((float4*)support)[(size_t)r * 32 + cg] = o;
        }
    }
}

// ---------------------------------------------------------------------------
// CSR build: memset -> histogram -> 3-phase scan -> payload scatter
// ---------------------------------------------------------------------------
__global__ void hist_kernel(const int* __restrict__ dst, int* __restrict__ counts, int e) {
    int i = blockIdx.x * blockDim.x + threadIdx.x;
    if (i < e) atomicAdd(&counts[dst[i]], 1);
}

__global__ void scan_phase1(const int* __restrict__ counts, int* __restrict__ partial,
                            int n, int chunk) {
    __shared__ int s[SCAN_T];
    int b = blockIdx.x, t = threadIdx.x;
    int base = b * chunk;
    int sum = 0;
    for (int i = t; i < chunk; i += SCAN_T) {
        int idx = base + i;
        if (idx < n) sum += counts[idx];
    }
    s[t] = sum; __syncthreads();
    #pragma unroll
    for (int off = 128; off; off >>= 1) {
        if (t < off) s[t] += s[t + off];
        __syncthreads();
    }
    if (t == 0) partial[b] = s[0];
}

__global__ void scan_phase2(int* __restrict__ partial) {
    __shared__ int s[SCAN_T];
    int t = threadIdx.x;
    int v = partial[t];
    s[t] = v; __syncthreads();
    for (int off = 1; off < SCAN_T; off <<= 1) {
        int x = (t >= off) ? s[t - off] : 0;
        __syncthreads();
        s[t] += x;
        __syncthreads();
    }
    partial[t] = s[t] - v;   // exclusive prefix of block sums
}

__global__ void scan_phase3(const int* __restrict__ counts, const int* __restrict__ partial,
                            int* __restrict__ row_ptr, int n, int chunk, int total) {
    __shared__ int s[SCAN_T];
    int b = blockIdx.x, t = threadIdx.x;
    int idx = b * chunk + t;
    int v = (t < chunk && idx < n) ? counts[idx] : 0;
    s[t] = v; __syncthreads();
    for (int off = 1; off < SCAN_T; off <<= 1) {
        int x = (t >= off) ? s[t - off] : 0;
        __syncthreads();
        s[t] += x;
        __syncthreads();
    }
    if (t < chunk && idx < n) row_ptr[idx] = partial[b] + s[t] - v;
    if (b == 0 && t == 0) row_ptr[n] = total;
}

// Writes sorted-by-dst payload: {src, bits(adj_val)} per edge slot.
__global__ void scatter_kernel(const int* __restrict__ dst, const int* __restrict__ src,
                               const float* __restrict__ adj_val,
                               const int* __restrict__ row_ptr,
                               int* __restrict__ counts, int2* __restrict__ payload, int e) {
    int i = blockIdx.x * blockDim.x + threadIdx.x;
    if (i < e) {
        int d = dst[i];
        int old = atomicSub(&counts[d], 1);   // drains counts back to 0
        payload[row_ptr[d] + old - 1] = make_int2(src[i], __float_as_int(adj_val[i]));
    }
}

// ---------------------------------------------------------------------------
// Aggregate: one WAVE per dst node (float2/lane = full 512B row per gather),
// 4 nodes per 256-thread block, edge loop unrolled x4 for MLP.
// ---------------------------------------------------------------------------
__global__ __launch_bounds__(256) void aggregate_kernel(
    const float* __restrict__ support, const int* __restrict__ row_ptr,
    const int2* __restrict__ payload, const float* __restrict__ bias,
    float* __restrict__ out, int Nn)
{
    const int gw = (int)((blockIdx.x * (unsigned)blockDim.x + threadIdx.x) >> 6);
    const int lane = threadIdx.x & 63;
    if (gw >= Nn) return;
    const int i0 = row_ptr[gw], i1 = row_ptr[gw + 1];
    const float2* __restrict__ sup2 = (const float2*)support;

    float ax = 0.f, ay = 0.f;
    int i = i0;
    for (; i + 4 <= i1; i += 4) {
        int2 p0 = payload[i];
        int2 p1 = payload[i + 1];
        int2 p2 = payload[i + 2];
        int2 p3 = payload[i + 3];
        float2 v0 = sup2[(size_t)p0.x * 64 + lane];
        float2 v1 = sup2[(size_t)p1.x * 64 + lane];
        float2 v2 = sup2[(size_t)p2.x * 64 + lane];
        float2 v3 = sup2[(size_t)p3.x * 64 + lane];
        float a0 = __int_as_float(p0.y), a1 = __int_as_float(p1.y);
        float a2 = __int_as_float(p2.y), a3 = __int_as_float(p3.y);
        ax = fmaf(a0, v0.x, ax); ay = fmaf(a0, v0.y, ay);
        ax = fmaf(a1, v1.x, ax); ay = fmaf(a1, v1.y, ay);
        ax = fmaf(a2, v2.x, ax); ay = fmaf(a2, v2.y, ay);
        ax = fmaf(a3, v3.x, ax); ay = fmaf(a3, v3.y, ay);
    }
    for (; i < i1; ++i) {
        int2 p = payload[i];
        float2 v = sup2[(size_t)p.x * 64 + lane];
        float a = __int_as_float(p.y);
        ax = fmaf(a, v.x, ax); ay = fmaf(a, v.y, ay);
    }

    float2 b = ((const float2*)bias)[lane];
    ((float2*)out)[(size_t)gw * 64 + lane] = make_float2(ax + b.x, ay + b.y);
}

// ---------------------------------------------------------------------------
// Fallback (ws too small for CSR): init out with bias, edge-parallel atomics.
// ---------------------------------------------------------------------------
__global__ void init_out_kernel(float* __restrict__ out, const float* __restrict__ bias, int n) {
    int i = blockIdx.x * blockDim.x + threadIdx.x;
    if (i < n) out[i] = bias[i & (F - 1)];
}

__global__ void edge_atomic_kernel(const float* __restrict__ support,
                                   const int* __restrict__ src, const int* __restrict__ dst,
                                   const float* __restrict__ adj_val, float* __restrict__ out, int e) {
    long long g = (long long)blockIdx.x * blockDim.x + threadIdx.x;
    if (g >= (long long)e * 32) return;
    int ed = (int)(g >> 5), q = (int)(g & 31);
    float a = adj_val[ed];
    float4 v = ((const float4*)support)[(size_t)src[ed] * 32 + q];
    float* o = out + (size_t)dst[ed] * F + 4 * q;
    atomicAdd(o + 0, a * v.x);
    atomicAdd(o + 1, a * v.y);
    atomicAdd(o + 2, a * v.z);
    atomicAdd(o + 3, a * v.w);
}

// ---------------------------------------------------------------------------
extern "C" void kernel_launch(void* const* d_in, const int* in_sizes, int n_in,
                              void* d_out, int out_size, void* d_ws, size_t ws_size,
                              hipStream_t stream) {
    const float* x       = (const float*)d_in[0];
    const float* weight  = (const float*)d_in[1];
    const float* node_w  = (const float*)d_in[2];
    const float* sem_w   = (const float*)d_in[3];
    const float* bias    = (const float*)d_in[4];
    const float* adj_val = (const float*)d_in[5];
    const int*   src     = (const int*)d_in[6];
    const int*   dst     = (const int*)d_in[7];
    float* out = (float*)d_out;

    const int Nn = in_sizes[0] / F;     // 40000
    const int Ee = in_sizes[5];         // 640000

    char* ws = (char*)d_ws;
    size_t off = 0;
    auto alloc = [&](size_t bytes) {
        void* p = ws + off;
        off = (off + bytes + 255) & ~(size_t)255;
        return p;
    };
    float* support  = (float*)alloc((size_t)Nn * F * sizeof(float));
    size_t need_atomic = off;
    int*  counts   = (int*)alloc((size_t)Nn * sizeof(int));
    int*  row_ptr  = (int*)alloc((size_t)(Nn + 1) * sizeof(int));
    int2* payload  = (int2*)alloc((size_t)Ee * sizeof(int2));
    int*  partial  = (int*)alloc(SCAN_T * sizeof(int));
    size_t need_full = off;

    // Stage 1: support GEMM (sem softmax + node att fused)
    support_kernel<<<(Nn + ROWS - 1) / ROWS, 256, 0, stream>>>(
        x, weight, node_w, sem_w, support, Nn);

    if (ws_size >= need_full) {
        const int chunk = (Nn + SCAN_B - 1) / SCAN_B;   // 157, <= SCAN_T
        hipMemsetAsync(counts, 0, (size_t)Nn * sizeof(int), stream);
        hist_kernel<<<(Ee + 255) / 256, 256, 0, stream>>>(dst, counts, Ee);
        scan_phase1<<<SCAN_B, SCAN_T, 0, stream>>>(counts, partial, Nn, chunk);
        scan_phase2<<<1, SCAN_T, 0, stream>>>(partial);
        scan_phase3<<<SCAN_B, SCAN_T, 0, stream>>>(counts, partial, row_ptr, Nn, chunk, Ee);
        scatter_kernel<<<(Ee + 255) / 256, 256, 0, stream>>>(dst, src, adj_val, row_ptr,
                                                             counts, payload, Ee);
        long long waves = (long long)Nn;            // one wave per node
        int blocks = (int)((waves * 64 + 255) / 256);
        aggregate_kernel<<<blocks, 256, 0, stream>>>(
            support, row_ptr, payload, bias, out, Nn);
    } else if (ws_size >= need_atomic) {
        init_out_kernel<<<((size_t)Nn * F + 255) / 256, 256, 0, stream>>>(out, bias, Nn * F);
        long long tot = (long long)Ee * 32;
        edge_atomic_kernel<<<(unsigned)((tot + 255) / 256), 256, 0, stream>>>(
            support, src, dst, adj_val, out, Ee);
    }
}

// Round 3
// 149.439 us; speedup vs baseline: 1.5777x; 1.0890x over previous
//
#include <hip/hip_runtime.h>
#include <hip/hip_bf16.h>

#define F 128
#define ROWS 32        // rows per block in support kernel
#define SCAN_T 256
#define SCAN_B 256

// ---------------------------------------------------------------------------
// support = (x * sigmoid(x@node_w) * softmax(sem_w)) @ weight
// One block = 32 rows, 256 threads. x tile (16KB) in LDS; W read from global
// (64KB, L1/L2-resident, shared by all blocks). 4x4 register tile per thread.
// ---------------------------------------------------------------------------
__global__ __launch_bounds__(256, 4) void support_kernel(
    const float* __restrict__ x, const float* __restrict__ weight,
    const float* __restrict__ node_w, const float* __restrict__ sem_w,
    float* __restrict__ support, int n_rows)
{
    __shared__ __align__(16) float xs[ROWS * F];     // [r][k] 16KB (scaled x)
    __shared__ __align__(16) float sem[F];
    __shared__ float natt[ROWS];

    const int t = threadIdx.x;
    const int rbase = blockIdx.x * ROWS;

    // --- semantic softmax (wave 0 only, 128 elems) ---
    if (t < 64) {
        float v0 = sem_w[t], v1 = sem_w[t + 64];
        float m = fmaxf(v0, v1);
        #pragma unroll
        for (int off = 32; off; off >>= 1) m = fmaxf(m, __shfl_xor(m, off));
        float e0 = __expf(v0 - m), e1 = __expf(v1 - m);
        float ssum = e0 + e1;
        #pragma unroll
        for (int off = 32; off; off >>= 1) ssum += __shfl_xor(ssum, off);
        float inv = 1.0f / ssum;
        sem[t] = e0 * inv;
        sem[t + 64] = e1 * inv;
    }

    // --- stage x tile + node-attention dot partials ---
    // j = t + i*256 indexes 1024 float4s: row r = j>>5, float4-col k4 = j&31.
    const int k4 = t & 31;
    float4 nw4 = ((const float4*)node_w)[k4];
    #pragma unroll
    for (int i = 0; i < 4; ++i) {
        int j = t + i * 256;
        int r = j >> 5;
        int gr = rbase + r;
        float4 v = make_float4(0.f, 0.f, 0.f, 0.f);
        if (gr < n_rows) v = ((const float4*)x)[(size_t)gr * 32 + k4];
        ((float4*)xs)[j] = v;
        float p = v.x * nw4.x + v.y * nw4.y + v.z * nw4.z + v.w * nw4.w;
        p += __shfl_xor(p, 1);  p += __shfl_xor(p, 2);  p += __shfl_xor(p, 4);
        p += __shfl_xor(p, 8);  p += __shfl_xor(p, 16);
        if ((t & 31) == 0) natt[r] = p;
    }
    __syncthreads();

    if (t < ROWS) {
        float z = natt[t];
        natt[t] = 1.0f / (1.0f + __expf(-z));
    }
    __syncthreads();

    // --- scale xs in place: xs[r][k] *= natt[r] * sem[k] ---
    #pragma unroll
    for (int i = 0; i < 4; ++i) {
        int j = t + i * 256;
        int r = j >> 5, kk = j & 31;
        float4 v = ((float4*)xs)[j];
        float4 s4 = ((float4*)sem)[kk];
        float a = natt[r];
        v.x *= a * s4.x; v.y *= a * s4.y; v.z *= a * s4.z; v.w *= a * s4.w;
        ((float4*)xs)[j] = v;
    }
    __syncthreads();

    // --- 4x4 register-tiled GEMM; W streamed from global (L1/L2-hot) ---
    const int cg = t & 31;
    const int rg = t >> 5;
    const float4* __restrict__ W4 = (const float4*)weight;
    float acc[4][4] = {};
    for (int k = 0; k < F; k += 4) {
        float4 w0 = W4[(k + 0) * 32 + cg];
        float4 w1 = W4[(k + 1) * 32 + cg];
        float4 w2 = W4[(k + 2) * 32 + cg];
        float4 w3 = W4[(k + 3) * 32 + cg];
        #pragma unroll
        for (int i = 0; i < 4; ++i) {
            float4 s = *(const float4*)&xs[(4 * rg + i) * F + k];
            acc[i][0] = fmaf(s.x, w0.x, acc[i][0]);
            acc[i][1] = fmaf(s.x, w0.y, acc[i][1]);
            acc[i][2] = fmaf(s.x, w0.z, acc[i][2]);
            acc[i][3] = fmaf(s.x, w0.w, acc[i][3]);
            acc[i][0] = fmaf(s.y, w1.x, acc[i][0]);
            acc[i][1] = fmaf(s.y, w1.y, acc[i][1]);
            acc[i][2] = fmaf(s.y, w1.z, acc[i][2]);
            acc[i][3] = fmaf(s.y, w1.w, acc[i][3]);
            acc[i][0] = fmaf(s.z, w2.x, acc[i][0]);
            acc[i][1] = fmaf(s.z, w2.y, acc[i][1]);
            acc[i][2] = fmaf(s.z, w2.z, acc[i][2]);
            acc[i][3] = fmaf(s.z, w2.w, acc[i][3]);
            acc[i][0] = fmaf(s.w, w3.x, acc[i][0]);
            acc[i][1] = fmaf(s.w, w3.y, acc[i][1]);
            acc[i][2] = fmaf(s.w, w3.z, acc[i][2]);
            acc[i][3] = fmaf(s.w, w3.w, acc[i][3]);
        }
    }

    #pragma unroll
    for (int i = 0; i < 4; ++i) {
        int r = rbase + 4 * rg + i;
        if (r < n_rows) {
            float4 o = make_float4(acc[i][0], acc[i][1], acc[i][2], acc[i][3]);
            ((float4*)support)[(size_t)r * 32 + cg] = o;
        }
    }
}

// ---------------------------------------------------------------------------
// CSR build: memset -> histogram -> 3-phase scan -> payload scatter
// ---------------------------------------------------------------------------
__global__ void hist_kernel(const int* __restrict__ dst, int* __restrict__ counts, int e) {
    int i = blockIdx.x * blockDim.x + threadIdx.x;
    if (i < e) atomicAdd(&counts[dst[i]], 1);
}

__global__ void scan_phase1(const int* __restrict__ counts, int* __restrict__ partial,
                            int n, int chunk) {
    __shared__ int s[SCAN_T];
    int b = blockIdx.x, t = threadIdx.x;
    int base = b * chunk;
    int sum = 0;
    for (int i = t; i < chunk; i += SCAN_T) {
        int idx = base + i;
        if (idx < n) sum += counts[idx];
    }
    s[t] = sum; __syncthreads();
    #pragma unroll
    for (int off = 128; off; off >>= 1) {
        if (t < off) s[t] += s[t + off];
        __syncthreads();
    }
    if (t == 0) partial[b] = s[0];
}

__global__ void scan_phase2(int* __restrict__ partial) {
    __shared__ int s[SCAN_T];
    int t = threadIdx.x;
    int v = partial[t];
    s[t] = v; __syncthreads();
    for (int off = 1; off < SCAN_T; off <<= 1) {
        int x = (t >= off) ? s[t - off] : 0;
        __syncthreads();
        s[t] += x;
        __syncthreads();
    }
    partial[t] = s[t] - v;   // exclusive prefix of block sums
}

__global__ void scan_phase3(const int* __restrict__ counts, const int* __restrict__ partial,
                            int* __restrict__ row_ptr, int n, int chunk, int total) {
    __shared__ int s[SCAN_T];
    int b = blockIdx.x, t = threadIdx.x;
    int idx = b * chunk + t;
    int v = (t < chunk && idx < n) ? counts[idx] : 0;
    s[t] = v; __syncthreads();
    for (int off = 1; off < SCAN_T; off <<= 1) {
        int x = (t >= off) ? s[t - off] : 0;
        __syncthreads();
        s[t] += x;
        __syncthreads();
    }
    if (t < chunk && idx < n) row_ptr[idx] = partial[b] + s[t] - v;
    if (b == 0 && t == 0) row_ptr[n] = total;
}

// Writes sorted-by-dst payload: {src, bits(adj_val)} per edge slot.
__global__ void scatter_kernel(const int* __restrict__ dst, const int* __restrict__ src,
                               const float* __restrict__ adj_val,
                               const int* __restrict__ row_ptr,
                               int* __restrict__ counts, int2* __restrict__ payload, int e) {
    int i = blockIdx.x * blockDim.x + threadIdx.x;
    if (i < e) {
        int d = dst[i];
        int old = atomicSub(&counts[d], 1);   // drains counts back to 0
        payload[row_ptr[d] + old - 1] = make_int2(src[i], __float_as_int(adj_val[i]));
    }
}

// ---------------------------------------------------------------------------
// Aggregate: one WAVE per dst node (float2/lane = full 512B row per gather),
// 4 nodes per 256-thread block, edge loop unrolled x4 for MLP.
// ---------------------------------------------------------------------------
__global__ __launch_bounds__(256) void aggregate_kernel(
    const float* __restrict__ support, const int* __restrict__ row_ptr,
    const int2* __restrict__ payload, const float* __restrict__ bias,
    float* __restrict__ out, int Nn)
{
    const int gw = (int)((blockIdx.x * (unsigned)blockDim.x + threadIdx.x) >> 6);
    const int lane = threadIdx.x & 63;
    if (gw >= Nn) return;
    const int i0 = row_ptr[gw], i1 = row_ptr[gw + 1];
    const float2* __restrict__ sup2 = (const float2*)support;

    float ax = 0.f, ay = 0.f;
    int i = i0;
    for (; i + 4 <= i1; i += 4) {
        int2 p0 = payload[i];
        int2 p1 = payload[i + 1];
        int2 p2 = payload[i + 2];
        int2 p3 = payload[i + 3];
        float2 v0 = sup2[(size_t)p0.x * 64 + lane];
        float2 v1 = sup2[(size_t)p1.x * 64 + lane];
        float2 v2 = sup2[(size_t)p2.x * 64 + lane];
        float2 v3 = sup2[(size_t)p3.x * 64 + lane];
        float a0 = __int_as_float(p0.y), a1 = __int_as_float(p1.y);
        float a2 = __int_as_float(p2.y), a3 = __int_as_float(p3.y);
        ax = fmaf(a0, v0.x, ax); ay = fmaf(a0, v0.y, ay);
        ax = fmaf(a1, v1.x, ax); ay = fmaf(a1, v1.y, ay);
        ax = fmaf(a2, v2.x, ax); ay = fmaf(a2, v2.y, ay);
        ax = fmaf(a3, v3.x, ax); ay = fmaf(a3, v3.y, ay);
    }
    for (; i < i1; ++i) {
        int2 p = payload[i];
        float2 v = sup2[(size_t)p.x * 64 + lane];
        float a = __int_as_float(p.y);
        ax = fmaf(a, v.x, ax); ay = fmaf(a, v.y, ay);
    }

    float2 b = ((const float2*)bias)[lane];
    ((float2*)out)[(size_t)gw * 64 + lane] = make_float2(ax + b.x, ay + b.y);
}

// ---------------------------------------------------------------------------
// Fallback (ws too small for CSR): init out with bias, edge-parallel atomics.
// ---------------------------------------------------------------------------
__global__ void init_out_kernel(float* __restrict__ out, const float* __restrict__ bias, int n) {
    int i = blockIdx.x * blockDim.x + threadIdx.x;
    if (i < n) out[i] = bias[i & (F - 1)];
}

__global__ void edge_atomic_kernel(const float* __restrict__ support,
                                   const int* __restrict__ src, const int* __restrict__ dst,
                                   const float* __restrict__ adj_val, float* __restrict__ out, int e) {
    long long g = (long long)blockIdx.x * blockDim.x + threadIdx.x;
    if (g >= (long long)e * 32) return;
    int ed = (int)(g >> 5), q = (int)(g & 31);
    float a = adj_val[ed];
    float4 v = ((const float4*)support)[(size_t)src[ed] * 32 + q];
    float* o = out + (size_t)dst[ed] * F + 4 * q;
    atomicAdd(o + 0, a * v.x);
    atomicAdd(o + 1, a * v.y);
    atomicAdd(o + 2, a * v.z);
    atomicAdd(o + 3, a * v.w);
}

// ---------------------------------------------------------------------------
extern "C" void kernel_launch(void* const* d_in, const int* in_sizes, int n_in,
                              void* d_out, int out_size, void* d_ws, size_t ws_size,
                              hipStream_t stream) {
    const float* x       = (const float*)d_in[0];
    const float* weight  = (const float*)d_in[1];
    const float* node_w  = (const float*)d_in[2];
    const float* sem_w   = (const float*)d_in[3];
    const float* bias    = (const float*)d_in[4];
    const float* adj_val = (const float*)d_in[5];
    const int*   src     = (const int*)d_in[6];
    const int*   dst     = (const int*)d_in[7];
    float* out = (float*)d_out;

    const int Nn = in_sizes[0] / F;     // 40000
    const int Ee = in_sizes[5];         // 640000

    char* ws = (char*)d_ws;
    size_t off = 0;
    auto alloc = [&](size_t bytes) {
        void* p = ws + off;
        off = (off + bytes + 255) & ~(size_t)255;
        return p;
    };
    float* support  = (float*)alloc((size_t)Nn * F * sizeof(float));
    size_t need_atomic = off;
    int*  counts   = (int*)alloc((size_t)Nn * sizeof(int));
    int*  row_ptr  = (int*)alloc((size_t)(Nn + 1) * sizeof(int));
    int2* payload  = (int2*)alloc((size_t)Ee * sizeof(int2));
    int*  partial  = (int*)alloc(SCAN_T * sizeof(int));
    size_t need_full = off;

    // Stage 1: support GEMM (sem softmax + node att fused)
    support_kernel<<<(Nn + ROWS - 1) / ROWS, 256, 0, stream>>>(
        x, weight, node_w, sem_w, support, Nn);

    if (ws_size >= need_full) {
        const int chunk = (Nn + SCAN_B - 1) / SCAN_B;   // 157, <= SCAN_T
        hipMemsetAsync(counts, 0, (size_t)Nn * sizeof(int), stream);
        hist_kernel<<<(Ee + 255) / 256, 256, 0, stream>>>(dst, counts, Ee);
        scan_phase1<<<SCAN_B, SCAN_T, 0, stream>>>(counts, partial, Nn, chunk);
        scan_phase2<<<1, SCAN_T, 0, stream>>>(partial);
        scan_phase3<<<SCAN_B, SCAN_T, 0, stream>>>(counts, partial, row_ptr, Nn, chunk, Ee);
        scatter_kernel<<<(Ee + 255) / 256, 256, 0, stream>>>(dst, src, adj_val, row_ptr,
                                                             counts, payload, Ee);
        long long waves = (long long)Nn;            // one wave per node
        int blocks = (int)((waves * 64 + 255) / 256);
        aggregate_kernel<<<blocks, 256, 0, stream>>>(
            support, row_ptr, payload, bias, out, Nn);
    } else if (ws_size >= need_atomic) {
        init_out_kernel<<<((size_t)Nn * F + 255) / 256, 256, 0, stream>>>(out, bias, Nn * F);
        long long tot = (long long)Ee * 32;
        edge_atomic_kernel<<<(unsigned)((tot + 255) / 256), 256, 0, stream>>>(
            support, src, dst, adj_val, out, Ee);
    }
}

// Round 4
// 122.930 us; speedup vs baseline: 1.9179x; 1.2156x over previous
//
#include <hip/hip_runtime.h>
#include <hip/hip_bf16.h>

#define F 128
#define ROWS 32        // rows per block in support kernel
#define SCAN_T 256
#define SCAN_B 256

// ---------------------------------------------------------------------------
// support = (x * sigmoid(x@node_w) * softmax(sem_w)) @ weight
// One block = 32 rows, 256 threads. x tile (16KB) in LDS; W read from global
// (64KB, L1/L2-resident, shared by all blocks). 4x4 register tile per thread.
// ---------------------------------------------------------------------------
__global__ __launch_bounds__(256, 4) void support_kernel(
    const float* __restrict__ x, const float* __restrict__ weight,
    const float* __restrict__ node_w, const float* __restrict__ sem_w,
    float* __restrict__ support, int n_rows)
{
    __shared__ __align__(16) float xs[ROWS * F];     // [r][k] 16KB (scaled x)
    __shared__ __align__(16) float sem[F];
    __shared__ float natt[ROWS];

    const int t = threadIdx.x;
    const int rbase = blockIdx.x * ROWS;

    // --- semantic softmax (wave 0 only, 128 elems) ---
    if (t < 64) {
        float v0 = sem_w[t], v1 = sem_w[t + 64];
        float m = fmaxf(v0, v1);
        #pragma unroll
        for (int off = 32; off; off >>= 1) m = fmaxf(m, __shfl_xor(m, off));
        float e0 = __expf(v0 - m), e1 = __expf(v1 - m);
        float ssum = e0 + e1;
        #pragma unroll
        for (int off = 32; off; off >>= 1) ssum += __shfl_xor(ssum, off);
        float inv = 1.0f / ssum;
        sem[t] = e0 * inv;
        sem[t + 64] = e1 * inv;
    }

    // --- stage x tile + node-attention dot partials ---
    const int k4 = t & 31;
    float4 nw4 = ((const float4*)node_w)[k4];
    #pragma unroll
    for (int i = 0; i < 4; ++i) {
        int j = t + i * 256;
        int r = j >> 5;
        int gr = rbase + r;
        float4 v = make_float4(0.f, 0.f, 0.f, 0.f);
        if (gr < n_rows) v = ((const float4*)x)[(size_t)gr * 32 + k4];
        ((float4*)xs)[j] = v;
        float p = v.x * nw4.x + v.y * nw4.y + v.z * nw4.z + v.w * nw4.w;
        p += __shfl_xor(p, 1);  p += __shfl_xor(p, 2);  p += __shfl_xor(p, 4);
        p += __shfl_xor(p, 8);  p += __shfl_xor(p, 16);
        if ((t & 31) == 0) natt[r] = p;
    }
    __syncthreads();

    if (t < ROWS) {
        float z = natt[t];
        natt[t] = 1.0f / (1.0f + __expf(-z));
    }
    __syncthreads();

    // --- scale xs in place: xs[r][k] *= natt[r] * sem[k] ---
    #pragma unroll
    for (int i = 0; i < 4; ++i) {
        int j = t + i * 256;
        int r = j >> 5, kk = j & 31;
        float4 v = ((float4*)xs)[j];
        float4 s4 = ((float4*)sem)[kk];
        float a = natt[r];
        v.x *= a * s4.x; v.y *= a * s4.y; v.z *= a * s4.z; v.w *= a * s4.w;
        ((float4*)xs)[j] = v;
    }
    __syncthreads();

    // --- 4x4 register-tiled GEMM; W streamed from global (L1/L2-hot) ---
    const int cg = t & 31;
    const int rg = t >> 5;
    const float4* __restrict__ W4 = (const float4*)weight;
    float acc[4][4] = {};
    for (int k = 0; k < F; k += 4) {
        float4 w0 = W4[(k + 0) * 32 + cg];
        float4 w1 = W4[(k + 1) * 32 + cg];
        float4 w2 = W4[(k + 2) * 32 + cg];
        float4 w3 = W4[(k + 3) * 32 + cg];
        #pragma unroll
        for (int i = 0; i < 4; ++i) {
            float4 s = *(const float4*)&xs[(4 * rg + i) * F + k];
            acc[i][0] = fmaf(s.x, w0.x, acc[i][0]);
            acc[i][1] = fmaf(s.x, w0.y, acc[i][1]);
            acc[i][2] = fmaf(s.x, w0.z, acc[i][2]);
            acc[i][3] = fmaf(s.x, w0.w, acc[i][3]);
            acc[i][0] = fmaf(s.y, w1.x, acc[i][0]);
            acc[i][1] = fmaf(s.y, w1.y, acc[i][1]);
            acc[i][2] = fmaf(s.y, w1.z, acc[i][2]);
            acc[i][3] = fmaf(s.y, w1.w, acc[i][3]);
            acc[i][0] = fmaf(s.z, w2.x, acc[i][0]);
            acc[i][1] = fmaf(s.z, w2.y, acc[i][1]);
            acc[i][2] = fmaf(s.z, w2.z, acc[i][2]);
            acc[i][3] = fmaf(s.z, w2.w, acc[i][3]);
            acc[i][0] = fmaf(s.w, w3.x, acc[i][0]);
            acc[i][1] = fmaf(s.w, w3.y, acc[i][1]);
            acc[i][2] = fmaf(s.w, w3.z, acc[i][2]);
            acc[i][3] = fmaf(s.w, w3.w, acc[i][3]);
        }
    }

    #pragma unroll
    for (int i = 0; i < 4; ++i) {
        int r = rbase + 4 * rg + i;
        if (r < n_rows) {
            float4 o = make_float4(acc[i][0], acc[i][1], acc[i][2], acc[i][3]);
            ((float4*)support)[(size_t)r * 32 + cg] = o;
        }
    }
}

// ---------------------------------------------------------------------------
// CSR build: memset -> hist(+slot) -> 3-phase scan -> atomic-free scatter
// ---------------------------------------------------------------------------
__global__ void hist_kernel(const int* __restrict__ dst, int* __restrict__ counts,
                            int* __restrict__ slot, int e) {
    int i = blockIdx.x * blockDim.x + threadIdx.x;
    if (i < e) slot[i] = atomicAdd(&counts[dst[i]], 1);   // slot store coalesced
}

__global__ void scan_phase1(const int* __restrict__ counts, int* __restrict__ partial,
                            int n, int chunk) {
    __shared__ int s[SCAN_T];
    int b = blockIdx.x, t = threadIdx.x;
    int base = b * chunk;
    int sum = 0;
    for (int i = t; i < chunk; i += SCAN_T) {
        int idx = base + i;
        if (idx < n) sum += counts[idx];
    }
    s[t] = sum; __syncthreads();
    #pragma unroll
    for (int off = 128; off; off >>= 1) {
        if (t < off) s[t] += s[t + off];
        __syncthreads();
    }
    if (t == 0) partial[b] = s[0];
}

__global__ void scan_phase2(int* __restrict__ partial) {
    __shared__ int s[SCAN_T];
    int t = threadIdx.x;
    int v = partial[t];
    s[t] = v; __syncthreads();
    for (int off = 1; off < SCAN_T; off <<= 1) {
        int x = (t >= off) ? s[t - off] : 0;
        __syncthreads();
        s[t] += x;
        __syncthreads();
    }
    partial[t] = s[t] - v;   // exclusive prefix of block sums
}

__global__ void scan_phase3(const int* __restrict__ counts, const int* __restrict__ partial,
                            int* __restrict__ row_ptr, int n, int chunk, int total) {
    __shared__ int s[SCAN_T];
    int b = blockIdx.x, t = threadIdx.x;
    int idx = b * chunk + t;
    int v = (t < chunk && idx < n) ? counts[idx] : 0;
    s[t] = v; __syncthreads();
    for (int off = 1; off < SCAN_T; off <<= 1) {
        int x = (t >= off) ? s[t - off] : 0;
        __syncthreads();
        s[t] += x;
        __syncthreads();
    }
    if (t < chunk && idx < n) row_ptr[idx] = partial[b] + s[t] - v;
    if (b == 0 && t == 0) row_ptr[n] = total;
}

// Atomic-free: pos = row_ptr[dst] + slot. Writes sorted-by-dst payload.
__global__ void scatter_kernel(const int* __restrict__ dst, const int* __restrict__ src,
                               const float* __restrict__ adj_val,
                               const int* __restrict__ row_ptr, const int* __restrict__ slot,
                               int2* __restrict__ payload, int e) {
    int i = blockIdx.x * blockDim.x + threadIdx.x;
    if (i < e) {
        int d = dst[i];
        payload[row_ptr[d] + slot[i]] = make_int2(src[i], __float_as_int(adj_val[i]));
    }
}

// ---------------------------------------------------------------------------
// Aggregate: one WAVE per dst node; 2 edges per gather instruction
// (half-wave each, float4/lane = 512B row per half), unroll x4 => 8 rows
// in flight. Cross-half shfl reduce, half 0 writes the row.
// ---------------------------------------------------------------------------
__global__ __launch_bounds__(256) void aggregate_kernel(
    const float* __restrict__ support, const int* __restrict__ row_ptr,
    const int2* __restrict__ payload, const float* __restrict__ bias,
    float* __restrict__ out, int Nn)
{
    const int gw = (int)((blockIdx.x * (unsigned)blockDim.x + threadIdx.x) >> 6);
    const int lane = threadIdx.x & 63;
    const int half = lane >> 5;
    const int l32  = lane & 31;
    if (gw >= Nn) return;
    const int i0 = row_ptr[gw], i1 = row_ptr[gw + 1];
    const float4* __restrict__ sup4 = (const float4*)support;

    float4 acc = make_float4(0.f, 0.f, 0.f, 0.f);
    int i = i0;
    for (; i + 8 <= i1; i += 8) {
        int2 p0 = payload[i + 0 + half];
        int2 p1 = payload[i + 2 + half];
        int2 p2 = payload[i + 4 + half];
        int2 p3 = payload[i + 6 + half];
        float4 v0 = sup4[(size_t)p0.x * 32 + l32];
        float4 v1 = sup4[(size_t)p1.x * 32 + l32];
        float4 v2 = sup4[(size_t)p2.x * 32 + l32];
        float4 v3 = sup4[(size_t)p3.x * 32 + l32];
        float a0 = __int_as_float(p0.y), a1 = __int_as_float(p1.y);
        float a2 = __int_as_float(p2.y), a3 = __int_as_float(p3.y);
        acc.x = fmaf(a0, v0.x, acc.x); acc.y = fmaf(a0, v0.y, acc.y);
        acc.z = fmaf(a0, v0.z, acc.z); acc.w = fmaf(a0, v0.w, acc.w);
        acc.x = fmaf(a1, v1.x, acc.x); acc.y = fmaf(a1, v1.y, acc.y);
        acc.z = fmaf(a1, v1.z, acc.z); acc.w = fmaf(a1, v1.w, acc.w);
        acc.x = fmaf(a2, v2.x, acc.x); acc.y = fmaf(a2, v2.y, acc.y);
        acc.z = fmaf(a2, v2.z, acc.z); acc.w = fmaf(a2, v2.w, acc.w);
        acc.x = fmaf(a3, v3.x, acc.x); acc.y = fmaf(a3, v3.y, acc.y);
        acc.z = fmaf(a3, v3.z, acc.z); acc.w = fmaf(a3, v3.w, acc.w);
    }
    for (; i + 2 <= i1; i += 2) {
        int2 p = payload[i + half];
        float4 v = sup4[(size_t)p.x * 32 + l32];
        float a = __int_as_float(p.y);
        acc.x = fmaf(a, v.x, acc.x); acc.y = fmaf(a, v.y, acc.y);
        acc.z = fmaf(a, v.z, acc.z); acc.w = fmaf(a, v.w, acc.w);
    }
    if (i < i1 && half == 0) {      // odd leftover edge -> half 0 only
        int2 p = payload[i];
        float4 v = sup4[(size_t)p.x * 32 + l32];
        float a = __int_as_float(p.y);
        acc.x = fmaf(a, v.x, acc.x); acc.y = fmaf(a, v.y, acc.y);
        acc.z = fmaf(a, v.z, acc.z); acc.w = fmaf(a, v.w, acc.w);
    }

    // cross-half reduction (lane ^ 32)
    acc.x += __shfl_xor(acc.x, 32);
    acc.y += __shfl_xor(acc.y, 32);
    acc.z += __shfl_xor(acc.z, 32);
    acc.w += __shfl_xor(acc.w, 32);

    if (half == 0) {
        float4 b = ((const float4*)bias)[l32];
        ((float4*)out)[(size_t)gw * 32 + l32] =
            make_float4(acc.x + b.x, acc.y + b.y, acc.z + b.z, acc.w + b.w);
    }
}

// ---------------------------------------------------------------------------
// Fallback (ws too small for CSR): init out with bias, edge-parallel atomics.
// ---------------------------------------------------------------------------
__global__ void init_out_kernel(float* __restrict__ out, const float* __restrict__ bias, int n) {
    int i = blockIdx.x * blockDim.x + threadIdx.x;
    if (i < n) out[i] = bias[i & (F - 1)];
}

__global__ void edge_atomic_kernel(const float* __restrict__ support,
                                   const int* __restrict__ src, const int* __restrict__ dst,
                                   const float* __restrict__ adj_val, float* __restrict__ out, int e) {
    long long g = (long long)blockIdx.x * blockDim.x + threadIdx.x;
    if (g >= (long long)e * 32) return;
    int ed = (int)(g >> 5), q = (int)(g & 31);
    float a = adj_val[ed];
    float4 v = ((const float4*)support)[(size_t)src[ed] * 32 + q];
    float* o = out + (size_t)dst[ed] * F + 4 * q;
    atomicAdd(o + 0, a * v.x);
    atomicAdd(o + 1, a * v.y);
    atomicAdd(o + 2, a * v.z);
    atomicAdd(o + 3, a * v.w);
}

// ---------------------------------------------------------------------------
extern "C" void kernel_launch(void* const* d_in, const int* in_sizes, int n_in,
                              void* d_out, int out_size, void* d_ws, size_t ws_size,
                              hipStream_t stream) {
    const float* x       = (const float*)d_in[0];
    const float* weight  = (const float*)d_in[1];
    const float* node_w  = (const float*)d_in[2];
    const float* sem_w   = (const float*)d_in[3];
    const float* bias    = (const float*)d_in[4];
    const float* adj_val = (const float*)d_in[5];
    const int*   src     = (const int*)d_in[6];
    const int*   dst     = (const int*)d_in[7];
    float* out = (float*)d_out;

    const int Nn = in_sizes[0] / F;     // 40000
    const int Ee = in_sizes[5];         // 640000

    char* ws = (char*)d_ws;
    size_t off = 0;
    auto alloc = [&](size_t bytes) {
        void* p = ws + off;
        off = (off + bytes + 255) & ~(size_t)255;
        return p;
    };
    float* support  = (float*)alloc((size_t)Nn * F * sizeof(float));
    size_t need_atomic = off;
    int*  counts   = (int*)alloc((size_t)Nn * sizeof(int));
    int*  row_ptr  = (int*)alloc((size_t)(Nn + 1) * sizeof(int));
    int2* payload  = (int2*)alloc((size_t)Ee * sizeof(int2));
    int*  partial  = (int*)alloc(SCAN_T * sizeof(int));
    size_t need_full = off;

    // slot[] lives in d_out (dead storage until aggregate fully rewrites it)
    int* slot = (int*)d_out;

    // Stage 1: support GEMM (sem softmax + node att fused)
    support_kernel<<<(Nn + ROWS - 1) / ROWS, 256, 0, stream>>>(
        x, weight, node_w, sem_w, support, Nn);

    if (ws_size >= need_full) {
        const int chunk = (Nn + SCAN_B - 1) / SCAN_B;   // 157, <= SCAN_T
        hipMemsetAsync(counts, 0, (size_t)Nn * sizeof(int), stream);
        hist_kernel<<<(Ee + 255) / 256, 256, 0, stream>>>(dst, counts, slot, Ee);
        scan_phase1<<<SCAN_B, SCAN_T, 0, stream>>>(counts, partial, Nn, chunk);
        scan_phase2<<<1, SCAN_T, 0, stream>>>(partial);
        scan_phase3<<<SCAN_B, SCAN_T, 0, stream>>>(counts, partial, row_ptr, Nn, chunk, Ee);
        scatter_kernel<<<(Ee + 255) / 256, 256, 0, stream>>>(dst, src, adj_val, row_ptr,
                                                             slot, payload, Ee);
        long long waves = (long long)Nn;            // one wave per node
        int blocks = (int)((waves * 64 + 255) / 256);
        aggregate_kernel<<<blocks, 256, 0, stream>>>(
            support, row_ptr, payload, bias, out, Nn);
    } else if (ws_size >= need_atomic) {
        init_out_kernel<<<((size_t)Nn * F + 255) / 256, 256, 0, stream>>>(out, bias, Nn * F);
        long long tot = (long long)Ee * 32;
        edge_atomic_kernel<<<(unsigned)((tot + 255) / 256), 256, 0, stream>>>(
            support, src, dst, adj_val, out, Ee);
    }
}